// Round 1
// baseline (2244.769 us; speedup 1.0000x reference)
//
#include <hip/hip_runtime.h>
#include <math.h>

#define BATCH 8
#define CH    256
#define NPIX  4096
#define CKDIM 64

// ---------------------------------------------------------------------------
// Kernel 0: fold the output 1x1 conv into v's weights.
// W'[o][c] = sum_m wg[o][m] * wv[m][c] ; b'[o] = sum_m wg[o][m] * bv[m]
// grid 256 blocks (o), 256 threads (c)
// ---------------------------------------------------------------------------
__global__ void fold_kernel(const float* __restrict__ wg, const float* __restrict__ wv,
                            const float* __restrict__ bv,
                            float* __restrict__ Wp, float* __restrict__ bp) {
    int o = blockIdx.x;
    int c = threadIdx.x;
    float acc = 0.f;
    for (int m = 0; m < CH; ++m)
        acc += wg[o * CH + m] * wv[m * CH + c];
    Wp[o * CH + c] = acc;
    if (c == 0) {
        float b = 0.f;
        for (int m = 0; m < CH; ++m) b += wg[o * CH + m] * bv[m];
        bp[o] = b;
    }
}

// ---------------------------------------------------------------------------
// Kernel 1: generic 1x1-conv GEMM  y[b][o][n] = sum_c W[o][c] x[b][c][n] + bias[o]
// grid (NPIX/256, O/32, BATCH), 256 threads. o-tile 32, n-tile 256, c-step 32.
// ---------------------------------------------------------------------------
__global__ void qkv_kernel(const float* __restrict__ Wm, const float* __restrict__ bias,
                           const float* __restrict__ x, float* __restrict__ y, int O) {
    __shared__ __align__(16) float Xl[32][256];   // 32 KB  [c][n]
    __shared__ __align__(16) float Wl[32][36];    // 4.6 KB [c][o] (stride 36: 16B-aligned rows)

    int n0  = blockIdx.x * 256;
    int o0  = blockIdx.y * 32;
    int b   = blockIdx.z;
    int tid = threadIdx.x;

    float acc[32];
#pragma unroll
    for (int o = 0; o < 32; ++o) acc[o] = 0.f;

    for (int c0 = 0; c0 < CH; c0 += 32) {
        __syncthreads();
        // stage X tile: 32 rows x 256 cols as float4 (8 per thread, coalesced)
#pragma unroll
        for (int r = 0; r < 8; ++r) {
            int f  = r * 256 + tid;       // float4 id, 0..2047
            int c  = f >> 6;              // 64 float4 per row
            int n4 = f & 63;
            float4 v = *(const float4*)(x + ((size_t)b * CH + c0 + c) * NPIX + n0 + n4 * 4);
            *(float4*)&Xl[c][n4 * 4] = v;
        }
        // stage W tile transposed: Wl[c][o] (coalesced global read over c)
#pragma unroll
        for (int r = 0; r < 4; ++r) {
            int f = r * 256 + tid;        // 0..1023
            int o = f >> 5;
            int c = f & 31;
            Wl[c][o] = Wm[(size_t)(o0 + o) * CH + c0 + c];
        }
        __syncthreads();
#pragma unroll 4
        for (int c = 0; c < 32; ++c) {
            float xv = Xl[c][tid];                          // lane-coalesced
            const float4* wrow = (const float4*)&Wl[c][0];  // wave-uniform broadcast
#pragma unroll
            for (int o4 = 0; o4 < 8; ++o4) {
                float4 w = wrow[o4];
                acc[o4 * 4 + 0] += w.x * xv;
                acc[o4 * 4 + 1] += w.y * xv;
                acc[o4 * 4 + 2] += w.z * xv;
                acc[o4 * 4 + 3] += w.w * xv;
            }
        }
    }
#pragma unroll
    for (int o = 0; o < 32; ++o)
        y[((size_t)b * O + o0 + o) * NPIX + n0 + tid] = acc[o] + bias[o0 + o];
}

// ---------------------------------------------------------------------------
// Kernel 2: fused attention.
// out[b][o][j] = sum_i v'[o][i] * elu(q[:,i].k[:,j]) / N + bg[o]
// grid (NPIX/64, BATCH), 512 threads. j-tile 64 (K staged once), i-tile 32.
// LDS = 16 + 8 + 32 + 8 = 64 KB -> 2 blocks/CU, 16 waves/CU.
// ---------------------------------------------------------------------------
#define JT 64
#define IT 32
__global__ void attn_kernel(const float* __restrict__ q, const float* __restrict__ k,
                            const float* __restrict__ vp, const float* __restrict__ bg,
                            float* __restrict__ out) {
    __shared__ __align__(16) float Kl[CKDIM][JT];   // 16 KB [ch][j]
    __shared__ __align__(16) float Ql[CKDIM][IT];   // 8 KB  [ch][i]
    __shared__ __align__(16) float Vl[CH][IT];      // 32 KB [o][i]
    __shared__ __align__(16) float Sl[IT][JT];      // 8 KB  [i][j]

    int b   = blockIdx.y;
    int j0  = blockIdx.x * JT;
    int tid = threadIdx.x;
    int j   = tid & 63;
    int g   = tid >> 6;    // 0..7, wave id

    // stage K tile once: 64x64 as float4 (2 per thread)
#pragma unroll
    for (int r = 0; r < 2; ++r) {
        int f  = r * 512 + tid;     // float4 id 0..1023
        int ch = f >> 4;            // 16 float4 per row
        int j4 = f & 15;
        float4 v = *(const float4*)(k + ((size_t)b * CKDIM + ch) * NPIX + j0 + j4 * 4);
        *(float4*)&Kl[ch][j4 * 4] = v;
    }

    float acc[32];
#pragma unroll
    for (int o = 0; o < 32; ++o) acc[o] = 0.f;

    for (int i0 = 0; i0 < NPIX; i0 += IT) {
        __syncthreads();   // previous iter's readers done (also covers first Kl use)
        // stage Q tile 64x32 (1 float4/thread)
        {
            int ch = tid >> 3;      // 8 float4 per row
            int i4 = tid & 7;
            float4 v = *(const float4*)(q + ((size_t)b * CKDIM + ch) * NPIX + i0 + i4 * 4);
            *(float4*)&Ql[ch][i4 * 4] = v;
        }
        // stage V' tile 256x32 (4 float4/thread)
#pragma unroll
        for (int r = 0; r < 4; ++r) {
            int f  = r * 512 + tid;
            int o  = f >> 3;
            int i4 = f & 7;
            float4 v = *(const float4*)(vp + ((size_t)b * CH + o) * NPIX + i0 + i4 * 4);
            *(float4*)&Vl[o][i4 * 4] = v;
        }
        __syncthreads();

        // ---- S phase: thread (j, g) computes S[g*4+m][j], m=0..3 ----
        float s[4] = {0.f, 0.f, 0.f, 0.f};
#pragma unroll 8
        for (int ch = 0; ch < CKDIM; ++ch) {
            float kv = Kl[ch][j];           // lane-coalesced
#pragma unroll
            for (int m = 0; m < 4; ++m)
                s[m] += Ql[ch][g * 4 + m] * kv;   // wave-uniform broadcast
        }
#pragma unroll
        for (int m = 0; m < 4; ++m) {
            float e = s[m];
            e = (e > 0.f) ? e : (__expf(e) - 1.f);   // elu
            Sl[g * 4 + m][j] = e * (1.f / (float)NPIX);
        }
        __syncthreads();

        // ---- accum phase: thread owns channels g*32..g*32+31 ----
#pragma unroll
        for (int ii = 0; ii < IT; ii += 4) {
            float s0 = Sl[ii + 0][j];
            float s1 = Sl[ii + 1][j];
            float s2 = Sl[ii + 2][j];
            float s3 = Sl[ii + 3][j];
#pragma unroll
            for (int o = 0; o < 32; ++o) {
                float4 v4 = *(const float4*)&Vl[g * 32 + o][ii];  // wave-uniform b128
                acc[o] += v4.x * s0 + v4.y * s1 + v4.z * s2 + v4.w * s3;
            }
        }
    }

    // epilogue: add bg, write final output (wg already folded into v')
#pragma unroll
    for (int o = 0; o < 32; ++o) {
        int oo = g * 32 + o;
        out[((size_t)b * CH + oo) * NPIX + j0 + j] = acc[o] + bg[oo];
    }
}

// ---------------------------------------------------------------------------
extern "C" void kernel_launch(void* const* d_in, const int* in_sizes, int n_in,
                              void* d_out, int out_size, void* d_ws, size_t ws_size,
                              hipStream_t stream) {
    const float* x  = (const float*)d_in[0];
    const float* wq = (const float*)d_in[1];
    const float* bq = (const float*)d_in[2];
    const float* wk = (const float*)d_in[3];
    const float* bk = (const float*)d_in[4];
    const float* wv = (const float*)d_in[5];
    const float* bv = (const float*)d_in[6];
    const float* wg = (const float*)d_in[7];
    const float* bg = (const float*)d_in[8];
    float* out = (float*)d_out;

    // workspace layout (floats): W' 65536 | b' 256 | q 2097152 | k 2097152 | v' 8388608
    float* Wp = (float*)d_ws;
    float* bp = Wp + 65536;
    float* qb = bp + 256;
    float* kb = qb + (size_t)BATCH * CKDIM * NPIX;
    float* vb = kb + (size_t)BATCH * CKDIM * NPIX;

    fold_kernel<<<dim3(256), dim3(256), 0, stream>>>(wg, wv, bv, Wp, bp);
    qkv_kernel<<<dim3(NPIX / 256, CKDIM / 32, BATCH), dim3(256), 0, stream>>>(wq, bq, x, qb, CKDIM);
    qkv_kernel<<<dim3(NPIX / 256, CKDIM / 32, BATCH), dim3(256), 0, stream>>>(wk, bk, x, kb, CKDIM);
    qkv_kernel<<<dim3(NPIX / 256, CH / 32, BATCH),    dim3(256), 0, stream>>>(Wp, bp, x, vb, CH);
    attn_kernel<<<dim3(NPIX / JT, BATCH), dim3(512), 0, stream>>>(qb, kb, vb, bg, out);
}

// Round 2
// 503.493 us; speedup vs baseline: 4.4584x; 4.4584x over previous
//
#include <hip/hip_runtime.h>
#include <math.h>

#define BATCH 8
#define CH    256
#define NPIX  4096
#define CKDIM 64

typedef __attribute__((ext_vector_type(8))) short short8;   // 8 bf16 (4 VGPRs)
typedef __attribute__((ext_vector_type(4))) float f32x4;    // MFMA accumulator

#define MFMA16x16(a, b, c) __builtin_amdgcn_mfma_f32_16x16x32_bf16((a), (b), (c), 0, 0, 0)

__device__ __forceinline__ unsigned short f2bf(float f) {
    union { float f; unsigned int u; } v; v.f = f;
    unsigned int u = v.u;
    u += 0x7fffu + ((u >> 16) & 1u);      // round-to-nearest-even
    return (unsigned short)(u >> 16);
}

// ---------------------------------------------------------------------------
// Kernel 0: fold output conv into v: W'[o][c] = sum_m wg[o][m] wv[m][c]
// ---------------------------------------------------------------------------
__global__ void fold_kernel(const float* __restrict__ wg, const float* __restrict__ wv,
                            const float* __restrict__ bv,
                            float* __restrict__ Wp, float* __restrict__ bp) {
    int o = blockIdx.x;
    int c = threadIdx.x;
    float acc = 0.f;
    for (int m = 0; m < CH; ++m)
        acc += wg[o * CH + m] * wv[m * CH + c];
    Wp[o * CH + c] = acc;
    if (c == 0) {
        float b = 0.f;
        for (int m = 0; m < CH; ++m) b += wg[o * CH + m] * bv[m];
        bp[o] = b;
    }
}

// ---------------------------------------------------------------------------
// Kernel 1a: q/k GEMM, fp32 accumulate, TRANSPOSED bf16 output y[b][n][64]
// grid (16, 2, 8), 256 threads. o-tile 32, n-tile 256.
// ---------------------------------------------------------------------------
__global__ void qkvT_kernel(const float* __restrict__ Wm, const float* __restrict__ bias,
                            const float* __restrict__ x, unsigned short* __restrict__ y) {
    __shared__ __align__(16) float Xl[32][256];
    __shared__ __align__(16) float Wl[32][36];

    int n0  = blockIdx.x * 256;
    int o0  = blockIdx.y * 32;
    int b   = blockIdx.z;
    int tid = threadIdx.x;

    float acc[32];
#pragma unroll
    for (int o = 0; o < 32; ++o) acc[o] = 0.f;

    for (int c0 = 0; c0 < CH; c0 += 32) {
        __syncthreads();
#pragma unroll
        for (int r = 0; r < 8; ++r) {
            int f  = r * 256 + tid;
            int c  = f >> 6;
            int n4 = f & 63;
            float4 v = *(const float4*)(x + ((size_t)b * CH + c0 + c) * NPIX + n0 + n4 * 4);
            *(float4*)&Xl[c][n4 * 4] = v;
        }
#pragma unroll
        for (int r = 0; r < 4; ++r) {
            int f = r * 256 + tid;
            int o = f >> 5;
            int c = f & 31;
            Wl[c][o] = Wm[(size_t)(o0 + o) * CH + c0 + c];
        }
        __syncthreads();
#pragma unroll 4
        for (int c = 0; c < 32; ++c) {
            float xv = Xl[c][tid];
            const float4* wrow = (const float4*)&Wl[c][0];
#pragma unroll
            for (int o4 = 0; o4 < 8; ++o4) {
                float4 w = wrow[o4];
                acc[o4 * 4 + 0] += w.x * xv;
                acc[o4 * 4 + 1] += w.y * xv;
                acc[o4 * 4 + 2] += w.z * xv;
                acc[o4 * 4 + 3] += w.w * xv;
            }
        }
    }
    // transposed bf16 write: y[b][n][o0..o0+31], 64 B contiguous per thread
    unsigned int pk[16];
#pragma unroll
    for (int p = 0; p < 16; ++p) {
        unsigned int lo = f2bf(acc[p * 2 + 0] + bias[o0 + p * 2 + 0]);
        unsigned int hi = f2bf(acc[p * 2 + 1] + bias[o0 + p * 2 + 1]);
        pk[p] = lo | (hi << 16);
    }
    unsigned short* dst = y + ((size_t)b * NPIX + n0 + tid) * CKDIM + o0;
#pragma unroll
    for (int p = 0; p < 4; ++p)
        *(uint4*)(dst + p * 8) = *(uint4*)&pk[p * 4];
}

// ---------------------------------------------------------------------------
// Kernel 1b: v' GEMM, bf16 output in [b][o][n] layout
// grid (16, 8, 8), 256 threads.
// ---------------------------------------------------------------------------
__global__ void qkvV_kernel(const float* __restrict__ Wm, const float* __restrict__ bias,
                            const float* __restrict__ x, unsigned short* __restrict__ y) {
    __shared__ __align__(16) float Xl[32][256];
    __shared__ __align__(16) float Wl[32][36];

    int n0  = blockIdx.x * 256;
    int o0  = blockIdx.y * 32;
    int b   = blockIdx.z;
    int tid = threadIdx.x;

    float acc[32];
#pragma unroll
    for (int o = 0; o < 32; ++o) acc[o] = 0.f;

    for (int c0 = 0; c0 < CH; c0 += 32) {
        __syncthreads();
#pragma unroll
        for (int r = 0; r < 8; ++r) {
            int f  = r * 256 + tid;
            int c  = f >> 6;
            int n4 = f & 63;
            float4 v = *(const float4*)(x + ((size_t)b * CH + c0 + c) * NPIX + n0 + n4 * 4);
            *(float4*)&Xl[c][n4 * 4] = v;
        }
#pragma unroll
        for (int r = 0; r < 4; ++r) {
            int f = r * 256 + tid;
            int o = f >> 5;
            int c = f & 31;
            Wl[c][o] = Wm[(size_t)(o0 + o) * CH + c0 + c];
        }
        __syncthreads();
#pragma unroll 4
        for (int c = 0; c < 32; ++c) {
            float xv = Xl[c][tid];
            const float4* wrow = (const float4*)&Wl[c][0];
#pragma unroll
            for (int o4 = 0; o4 < 8; ++o4) {
                float4 w = wrow[o4];
                acc[o4 * 4 + 0] += w.x * xv;
                acc[o4 * 4 + 1] += w.y * xv;
                acc[o4 * 4 + 2] += w.z * xv;
                acc[o4 * 4 + 3] += w.w * xv;
            }
        }
    }
#pragma unroll
    for (int o = 0; o < 32; ++o)
        y[((size_t)b * CH + o0 + o) * NPIX + n0 + tid] = f2bf(acc[o] + bias[o0 + o]);
}

// ---------------------------------------------------------------------------
// Kernel 2: MFMA attention.  out[b][o][j] = sum_i v'[o][i] * elu(q.k)/N + bg[o]
// grid (64, 8), 512 threads (8 waves). j-tile 64, i-tile 64, all 256 channels.
// LDS 63 KB -> 2 blocks/CU.
// ---------------------------------------------------------------------------
#define LP 72   // padded row stride (bf16 elems): 144 B = 36 dwords -> 4-bank rotate
__global__ __launch_bounds__(512, 4)
void attn_mfma(const unsigned short* __restrict__ qt,  // [B][N][64] bf16
               const unsigned short* __restrict__ kt,  // [B][N][64] bf16
               const unsigned short* __restrict__ vp,  // [B][256][N] bf16
               const float* __restrict__ bg,
               float* __restrict__ out) {
    __shared__ __align__(16) unsigned short Kt[64][LP];   // [j][ch]
    __shared__ __align__(16) unsigned short Qt[64][LP];   // [i][ch]
    __shared__ __align__(16) unsigned short Vl[256][LP];  // [o][i]
    __shared__ __align__(16) unsigned short St[64][LP];   // [j][i]

    int b    = blockIdx.y;
    int j0   = blockIdx.x * 64;
    int tid  = threadIdx.x;
    int lane = tid & 63;
    int w    = tid >> 6;
    int col  = lane & 15;
    int quad = lane >> 4;

    // stage K tile once: 64 rows x 64ch (1 uint4/thread)
    {
        int row = tid >> 3, q4 = tid & 7;
        uint4 d = *(const uint4*)(kt + ((size_t)b * NPIX + j0 + row) * CKDIM + q4 * 8);
        *(uint4*)&Kt[row][q4 * 8] = d;
    }

    f32x4 acc[2][4];
#pragma unroll
    for (int a = 0; a < 2; ++a)
#pragma unroll
        for (int t = 0; t < 4; ++t) acc[a][t] = (f32x4){0.f, 0.f, 0.f, 0.f};

    const int ti0 = (w >> 2) * 2;   // phase-A i-tile pair
    const int tjA = w & 3;          // phase-A j-tile

    for (int i0 = 0; i0 < NPIX; i0 += 64) {
        __syncthreads();   // prev iter readers done (covers first Kt use too)
        // stage Q tile (1 uint4/thread) and V' tile (4 uint4/thread)
        {
            int row = tid >> 3, q4 = tid & 7;
            uint4 d = *(const uint4*)(qt + ((size_t)b * NPIX + i0 + row) * CKDIM + q4 * 8);
            *(uint4*)&Qt[row][q4 * 8] = d;
        }
#pragma unroll
        for (int r = 0; r < 4; ++r) {
            int f = r * 512 + tid;
            int o = f >> 3, q4 = f & 7;
            uint4 d = *(const uint4*)(vp + ((size_t)b * CH + o) * NPIX + i0 + q4 * 8);
            *(uint4*)&Vl[o][q4 * 8] = d;
        }
        __syncthreads();

        // ---- phase A: S[64x64] = Q_tile^T-dot-K_tile, elu, -> St bf16 ----
        {
            short8 bf0 = *(const short8*)&Kt[tjA * 16 + col][quad * 8];
            short8 bf1 = *(const short8*)&Kt[tjA * 16 + col][quad * 8 + 32];
#pragma unroll
            for (int t = 0; t < 2; ++t) {
                int mrow = (ti0 + t) * 16 + col;
                short8 a0 = *(const short8*)&Qt[mrow][quad * 8];
                short8 a1 = *(const short8*)&Qt[mrow][quad * 8 + 32];
                f32x4 s = (f32x4){0.f, 0.f, 0.f, 0.f};
                s = MFMA16x16(a0, bf0, s);
                s = MFMA16x16(a1, bf1, s);
                unsigned int pk[2];
#pragma unroll
                for (int p = 0; p < 2; ++p) {
                    float e0 = s[p * 2 + 0];
                    float e1 = s[p * 2 + 1];
                    e0 = (e0 > 0.f) ? e0 : (__expf(e0) - 1.f);
                    e1 = (e1 > 0.f) ? e1 : (__expf(e1) - 1.f);
                    e0 *= (1.f / (float)NPIX);
                    e1 *= (1.f / (float)NPIX);
                    pk[p] = (unsigned int)f2bf(e0) | ((unsigned int)f2bf(e1) << 16);
                }
                // C-layout: col=lane&15 (j), row=quad*4+r (i, contiguous) -> b64 write
                *(uint2*)&St[tjA * 16 + col][(ti0 + t) * 16 + quad * 4] = *(uint2*)pk;
            }
        }
        __syncthreads();

        // ---- phase B: acc[256x64] += V'[256x64] . St[64x64]^T ----
#pragma unroll
        for (int ks = 0; ks < 2; ++ks) {
            short8 sb[4];
#pragma unroll
            for (int tj = 0; tj < 4; ++tj)
                sb[tj] = *(const short8*)&St[tj * 16 + col][quad * 8 + 32 * ks];
#pragma unroll
            for (int ot = 0; ot < 2; ++ot) {
                short8 av = *(const short8*)&Vl[(w * 2 + ot) * 16 + col][quad * 8 + 32 * ks];
#pragma unroll
                for (int tj = 0; tj < 4; ++tj)
                    acc[ot][tj] = MFMA16x16(av, sb[tj], acc[ot][tj]);
            }
        }
    }

    // epilogue: C-layout scatter + bias
#pragma unroll
    for (int ot = 0; ot < 2; ++ot) {
        int ob = (w * 2 + ot) * 16 + quad * 4;
#pragma unroll
        for (int tj = 0; tj < 4; ++tj) {
#pragma unroll
            for (int r = 0; r < 4; ++r) {
                int o = ob + r;
                out[((size_t)b * CH + o) * NPIX + j0 + tj * 16 + col] = acc[ot][tj][r] + bg[o];
            }
        }
    }
}

// ---------------------------------------------------------------------------
extern "C" void kernel_launch(void* const* d_in, const int* in_sizes, int n_in,
                              void* d_out, int out_size, void* d_ws, size_t ws_size,
                              hipStream_t stream) {
    const float* x  = (const float*)d_in[0];
    const float* wq = (const float*)d_in[1];
    const float* bq = (const float*)d_in[2];
    const float* wk = (const float*)d_in[3];
    const float* bk = (const float*)d_in[4];
    const float* wv = (const float*)d_in[5];
    const float* bv = (const float*)d_in[6];
    const float* wg = (const float*)d_in[7];
    const float* bg = (const float*)d_in[8];
    float* out = (float*)d_out;

    // ws: W' 65536 f | b' 256 f | q 2.1M bf16 | k 2.1M bf16 | v' 8.4M bf16
    float* Wp = (float*)d_ws;
    float* bp = Wp + 65536;
    unsigned short* qb = (unsigned short*)(bp + 256);
    unsigned short* kb = qb + (size_t)BATCH * NPIX * CKDIM;
    unsigned short* vb = kb + (size_t)BATCH * NPIX * CKDIM;

    fold_kernel<<<dim3(256), dim3(256), 0, stream>>>(wg, wv, bv, Wp, bp);
    qkvT_kernel<<<dim3(NPIX / 256, CKDIM / 32, BATCH), dim3(256), 0, stream>>>(wq, bq, x, qb);
    qkvT_kernel<<<dim3(NPIX / 256, CKDIM / 32, BATCH), dim3(256), 0, stream>>>(wk, bk, x, kb);
    qkvV_kernel<<<dim3(NPIX / 256, CH / 32, BATCH),    dim3(256), 0, stream>>>(Wp, bp, x, vb);
    attn_mfma<<<dim3(NPIX / 64, BATCH), dim3(512), 0, stream>>>(qb, kb, vb, bg, out);
}

// Round 3
// 344.371 us; speedup vs baseline: 6.5185x; 1.4621x over previous
//
#include <hip/hip_runtime.h>
#include <math.h>

#define BATCH 8
#define CH    256
#define NPIX  4096
#define CKDIM 64

typedef __attribute__((ext_vector_type(8))) short short8;   // 8 bf16 (4 VGPRs)
typedef __attribute__((ext_vector_type(4))) float f32x4;    // MFMA accumulator

#define MFMA16x16(a, b, c) __builtin_amdgcn_mfma_f32_16x16x32_bf16((a), (b), (c), 0, 0, 0)

__device__ __forceinline__ unsigned short f2bf(float f) {
    union { float f; unsigned int u; } v; v.f = f;
    unsigned int u = v.u;
    u += 0x7fffu + ((u >> 16) & 1u);      // round-to-nearest-even
    return (unsigned short)(u >> 16);
}

// ---------------------------------------------------------------------------
// Kernel P: build W_all[384][256] bf16 (rows: 0-63 wq, 64-127 wk, 128-383 wg@wv)
// and bias_all[384] fp32. grid 384 x 256 threads.
// ---------------------------------------------------------------------------
__global__ void prep_kernel(const float* __restrict__ wq, const float* __restrict__ bq,
                            const float* __restrict__ wk, const float* __restrict__ bk,
                            const float* __restrict__ wv, const float* __restrict__ bv,
                            const float* __restrict__ wg,
                            unsigned short* __restrict__ W_all, float* __restrict__ bias_all) {
    int o = blockIdx.x;
    int c = threadIdx.x;
    if (o < 64) {
        W_all[o * CH + c] = f2bf(wq[o * CH + c]);
        if (c == 0) bias_all[o] = bq[o];
    } else if (o < 128) {
        int oo = o - 64;
        W_all[o * CH + c] = f2bf(wk[oo * CH + c]);
        if (c == 0) bias_all[o] = bk[oo];
    } else {
        int oo = o - 128;
        float acc = 0.f;
        for (int m = 0; m < CH; ++m)
            acc += wg[oo * CH + m] * wv[m * CH + c];
        W_all[o * CH + c] = f2bf(acc);
        if (c == 0) {
            float b = 0.f;
            for (int m = 0; m < CH; ++m) b += wg[oo * CH + m] * bv[m];
            bias_all[o] = b;
        }
    }
}

// ---------------------------------------------------------------------------
// Kernel T: transpose+convert x[b][c][n] fp32 -> xt[b][n][c] bf16.
// 64x64 tiles, 256 threads. LDS stride 65 (scalar b32 ops, <=2-way banks).
// grid (64, 4, 8).
// ---------------------------------------------------------------------------
__global__ void xpose_kernel(const float* __restrict__ x, unsigned short* __restrict__ xt) {
    __shared__ float Tl[64][65];   // [n][c]
    int n0 = blockIdx.x * 64;
    int c0 = blockIdx.y * 64;
    int b  = blockIdx.z;
    int tid = threadIdx.x;

    // read 64c x 64n fp32, coalesced float4 (4 per thread)
#pragma unroll
    for (int r = 0; r < 4; ++r) {
        int f  = r * 256 + tid;
        int c  = f >> 4;           // 16 float4 per c-row
        int n4 = f & 15;
        float4 v = *(const float4*)(x + ((size_t)b * CH + c0 + c) * NPIX + n0 + n4 * 4);
        Tl[n4 * 4 + 0][c] = v.x;
        Tl[n4 * 4 + 1][c] = v.y;
        Tl[n4 * 4 + 2][c] = v.z;
        Tl[n4 * 4 + 3][c] = v.w;
    }
    __syncthreads();
    // write 64n x 64c bf16, coalesced uint4 (2 per thread)
#pragma unroll
    for (int r = 0; r < 2; ++r) {
        int f    = r * 256 + tid;
        int nrow = f >> 3;         // 8 uint4 per n-row
        int c8   = f & 7;
        unsigned int pk[4];
#pragma unroll
        for (int p = 0; p < 4; ++p) {
            unsigned int lo = f2bf(Tl[nrow][c8 * 8 + p * 2 + 0]);
            unsigned int hi = f2bf(Tl[nrow][c8 * 8 + p * 2 + 1]);
            pk[p] = lo | (hi << 16);
        }
        *(uint4*)(xt + ((size_t)b * NPIX + n0 + nrow) * CH + c0 + c8 * 8) = *(uint4*)pk;
    }
}

// ---------------------------------------------------------------------------
// Kernel G: all-global MFMA GEMM. y[o][n] = sum_c W_all[o][c] xt[n][c] + bias.
// o<128 -> qk[b][n][128] transposed; o>=128 -> vp[b][o-128][n].
// grid (64, 6, 8), 256 threads (4 waves). No LDS.
// ---------------------------------------------------------------------------
__global__ void qkv_mfma(const unsigned short* __restrict__ xt,
                         const unsigned short* __restrict__ W_all,
                         const float* __restrict__ bias_all,
                         unsigned short* __restrict__ qk, unsigned short* __restrict__ vp) {
    int n0   = blockIdx.x * 64;
    int o0   = blockIdx.y * 64;
    int b    = blockIdx.z;
    int lane = threadIdx.x & 63;
    int w    = threadIdx.x >> 6;
    int col  = lane & 15;
    int quad = lane >> 4;

    const unsigned short* Arow = W_all + (size_t)(o0 + w * 16 + col) * CH + quad * 8;

    f32x4 acc[4];
#pragma unroll
    for (int t = 0; t < 4; ++t) acc[t] = (f32x4){0.f, 0.f, 0.f, 0.f};

#pragma unroll
    for (int kc = 0; kc < 8; ++kc) {        // K = 256 in chunks of 32
        short8 a = *(const short8*)(Arow + kc * 32);
#pragma unroll
        for (int nt = 0; nt < 4; ++nt) {
            short8 bb = *(const short8*)(xt + ((size_t)b * NPIX + n0 + nt * 16 + col) * CH + kc * 32 + quad * 8);
            acc[nt] = MFMA16x16(a, bb, acc[nt]);
        }
    }

    float4 bias = *(const float4*)(bias_all + o0 + w * 16 + quad * 4);
    float bs[4] = {bias.x, bias.y, bias.z, bias.w};

    if (o0 < 128) {
        // q/k: transposed store qk[b][n][o], 4 bf16 (uint2) per tile
#pragma unroll
        for (int nt = 0; nt < 4; ++nt) {
            int n = n0 + nt * 16 + col;
            unsigned int pk[2];
#pragma unroll
            for (int p = 0; p < 2; ++p) {
                unsigned int lo = f2bf(acc[nt][p * 2 + 0] + bs[p * 2 + 0]);
                unsigned int hi = f2bf(acc[nt][p * 2 + 1] + bs[p * 2 + 1]);
                pk[p] = lo | (hi << 16);
            }
            *(uint2*)(qk + ((size_t)b * NPIX + n) * 128 + o0 + w * 16 + quad * 4) = *(uint2*)pk;
        }
    } else {
        // v': vp[b][o'][n]
#pragma unroll
        for (int nt = 0; nt < 4; ++nt) {
            int n = n0 + nt * 16 + col;
#pragma unroll
            for (int r = 0; r < 4; ++r) {
                int oo = o0 - 128 + w * 16 + quad * 4 + r;
                vp[((size_t)b * CH + oo) * NPIX + n] = f2bf(acc[nt][r] + bs[r]);
            }
        }
    }
}

// ---------------------------------------------------------------------------
// Kernel A: attention. j-tile 128, i-tile 64, 8 waves (4 o-split x 2 j-split).
// Q,V fragments from global (L2), prefetched one i-tile ahead. K + S^T in LDS.
// grid 256 (= 1 block/CU; id&7 = batch for XCD-L2 locality), 512 threads.
// ---------------------------------------------------------------------------
#define LPK 72
__global__ __launch_bounds__(512, 2)
void attn_v2(const unsigned short* __restrict__ qk,   // [B][N][128]: q=0..63, k=64..127
             const unsigned short* __restrict__ vp,   // [B][256][N]
             const float* __restrict__ bg, float* __restrict__ out) {
    __shared__ __align__(16) unsigned short Kt[128][LPK];  // [j][ch]   18 KB
    __shared__ __align__(16) unsigned short St[128][LPK];  // [j][i]    18 KB

    int id   = blockIdx.x;
    int b    = id & 7;            // XCD-local batch
    int j0   = (id >> 3) * 128;
    int tid  = threadIdx.x;
    int lane = tid & 63;
    int w    = tid >> 6;
    int col  = lane & 15;
    int quad = lane >> 4;

    // stage K tile once: 128 rows x 64 ch (2 uint4/thread)
#pragma unroll
    for (int r = 0; r < 2; ++r) {
        int f = r * 512 + tid;
        int row = f >> 3, q8 = f & 7;
        *(uint4*)&Kt[row][q8 * 8] =
            *(const uint4*)(qk + ((size_t)b * NPIX + j0 + row) * 128 + 64 + q8 * 8);
    }

    // phase-A map: 2 ti x 2 tj per wave ; phase-B map: 4 ot x 4 tj per wave
    int tiB = (w >> 2) * 2;       // i-tile base (phase A)
    int tjA = (w & 3) * 2;        // j-tile base (phase A)
    int wo  = w >> 1;             // o 64-block  (phase B)
    int wjB = w & 1;              // j 64-half   (phase B)

    // prefetch Q fragments (i0 = 0): aQ[ti][ks]
    uint4 aQ[2][2];
#pragma unroll
    for (int t = 0; t < 2; ++t)
#pragma unroll
        for (int ks = 0; ks < 2; ++ks)
            aQ[t][ks] = *(const uint4*)(qk + ((size_t)b * NPIX + (tiB + t) * 16 + col) * 128 + ks * 32 + quad * 8);
    // prefetch V fragments: aV[ot][ks]
    uint4 aV[4][2];
#pragma unroll
    for (int ot = 0; ot < 4; ++ot)
#pragma unroll
        for (int ks = 0; ks < 2; ++ks)
            aV[ot][ks] = *(const uint4*)(vp + ((size_t)b * CH + wo * 64 + ot * 16 + col) * NPIX + ks * 32 + quad * 8);

    f32x4 acc[4][4];
#pragma unroll
    for (int ot = 0; ot < 4; ++ot)
#pragma unroll
        for (int tj = 0; tj < 4; ++tj) acc[ot][tj] = (f32x4){0.f, 0.f, 0.f, 0.f};

    __syncthreads();   // Kt ready

    for (int i0 = 0; i0 < NPIX; i0 += 64) {
        int inext = (i0 + 64) & (NPIX - 1);

        // ---- phase A: S[64x128] = Q.K^T, elu/N, -> St[j][i] bf16 ----
        short8 bK[2][2];
#pragma unroll
        for (int t2 = 0; t2 < 2; ++t2)
#pragma unroll
            for (int ks = 0; ks < 2; ++ks)
                bK[t2][ks] = *(const short8*)&Kt[(tjA + t2) * 16 + col][ks * 32 + quad * 8];
#pragma unroll
        for (int t = 0; t < 2; ++t) {
#pragma unroll
            for (int t2 = 0; t2 < 2; ++t2) {
                f32x4 s = (f32x4){0.f, 0.f, 0.f, 0.f};
                s = MFMA16x16(*(const short8*)&aQ[t][0], bK[t2][0], s);
                s = MFMA16x16(*(const short8*)&aQ[t][1], bK[t2][1], s);
                unsigned int pk[2];
#pragma unroll
                for (int p = 0; p < 2; ++p) {
                    float e0 = s[p * 2 + 0];
                    float e1 = s[p * 2 + 1];
                    e0 = (e0 > 0.f) ? e0 : (__expf(e0) - 1.f);
                    e1 = (e1 > 0.f) ? e1 : (__expf(e1) - 1.f);
                    e0 *= (1.f / (float)NPIX);
                    e1 *= (1.f / (float)NPIX);
                    pk[p] = (unsigned int)f2bf(e0) | ((unsigned int)f2bf(e1) << 16);
                }
                *(uint2*)&St[(tjA + t2) * 16 + col][(tiB + t) * 16 + quad * 4] = *(uint2*)pk;
            }
        }
        // prefetch next Q
#pragma unroll
        for (int t = 0; t < 2; ++t)
#pragma unroll
            for (int ks = 0; ks < 2; ++ks)
                aQ[t][ks] = *(const uint4*)(qk + ((size_t)b * NPIX + inext + (tiB + t) * 16 + col) * 128 + ks * 32 + quad * 8);
        __syncthreads();   // St written

        // ---- phase B: acc[256x128] += V'[256x64] . St^T ----
#pragma unroll
        for (int ks = 0; ks < 2; ++ks) {
            short8 sb[4];
#pragma unroll
            for (int tj = 0; tj < 4; ++tj)
                sb[tj] = *(const short8*)&St[(wjB * 4 + tj) * 16 + col][ks * 32 + quad * 8];
#pragma unroll
            for (int ot = 0; ot < 4; ++ot)
#pragma unroll
                for (int tj = 0; tj < 4; ++tj)
                    acc[ot][tj] = MFMA16x16(*(const short8*)&aV[ot][ks], sb[tj], acc[ot][tj]);
        }
        // prefetch next V
#pragma unroll
        for (int ot = 0; ot < 4; ++ot)
#pragma unroll
            for (int ks = 0; ks < 2; ++ks)
                aV[ot][ks] = *(const uint4*)(vp + ((size_t)b * CH + wo * 64 + ot * 16 + col) * NPIX + inext + ks * 32 + quad * 8);
        __syncthreads();   // St consumed
    }

    // epilogue: C-layout scatter + bg
#pragma unroll
    for (int ot = 0; ot < 4; ++ot) {
        int ob = wo * 64 + ot * 16 + quad * 4;
#pragma unroll
        for (int tj = 0; tj < 4; ++tj) {
            int j = j0 + wjB * 64 + tj * 16 + col;
#pragma unroll
            for (int r = 0; r < 4; ++r) {
                int o = ob + r;
                out[((size_t)b * CH + o) * NPIX + j] = acc[ot][tj][r] + bg[o];
            }
        }
    }
}

// ---------------------------------------------------------------------------
extern "C" void kernel_launch(void* const* d_in, const int* in_sizes, int n_in,
                              void* d_out, int out_size, void* d_ws, size_t ws_size,
                              hipStream_t stream) {
    const float* x  = (const float*)d_in[0];
    const float* wq = (const float*)d_in[1];
    const float* bq = (const float*)d_in[2];
    const float* wk = (const float*)d_in[3];
    const float* bk = (const float*)d_in[4];
    const float* wv = (const float*)d_in[5];
    const float* bv = (const float*)d_in[6];
    const float* wg = (const float*)d_in[7];
    const float* bg = (const float*)d_in[8];
    float* out = (float*)d_out;

    // ws layout: W_all 384*256 bf16 | bias_all 384 f32 | xt 8*4096*256 bf16 |
    //            qk 8*4096*128 bf16 | vp 8*256*4096 bf16   (~42 MB)
    unsigned short* W_all = (unsigned short*)d_ws;
    float* bias_all = (float*)(W_all + 384 * 256);
    unsigned short* xt = (unsigned short*)(bias_all + 384);
    unsigned short* qk = xt + (size_t)BATCH * NPIX * CH;
    unsigned short* vp = qk + (size_t)BATCH * NPIX * 128;

    prep_kernel<<<dim3(384), dim3(256), 0, stream>>>(wq, bq, wk, bk, wv, bv, wg, W_all, bias_all);
    xpose_kernel<<<dim3(NPIX / 64, CH / 64, BATCH), dim3(256), 0, stream>>>(x, xt);
    qkv_mfma<<<dim3(NPIX / 64, 6, BATCH), dim3(256), 0, stream>>>(xt, W_all, bias_all, qk, vp);
    attn_v2<<<dim3(256), dim3(512), 0, stream>>>(qk, vp, bg, out);
}